// Round 22
// baseline (42.351 us; speedup 1.0000x reference)
//
#include <hip/hip_runtime.h>

// ContinuityLoss: loss = 0.01/(n(n-1)) * sum_{i!=j} exp(-|pi-pj|^2/2) * |oi-oj|
// points: [N,2] f32, outputs: [N,8] f32, scalar f32 out. N = 8192.
//
// R21 = R16 (23.1us anchor) with ONE change: cont_final deleted; each
// pairs-block finishes with a single f32 atomicAdd(out, blocksum*scale)
// (device-scope HW atomic, NO fences - R15 showed explicit fences cost
// ~60us; R18 proved the atomic finish itself validates, absmax 0.0, but
// bundled it with a VGPR-blowing strip change - this isolates it).
// 2064 staggered atomics to one address sit off the critical path.
// d_out zeroed per call via 4-byte hipMemsetAsync (graph-capturable).
// Everything else R16-verbatim:
//  - prep kernel: lane-exact fragment tables AO/AP/BO/BP[512][64]
//    (h4, 1MB, L2-resident)
//  - pairs kernel: 2064 4-wave blocks, one 64x64 tile per wave:
//    16 coalesced 8B fragment loads + 32 MFMA + {fmax,sqrt,exp2,fma}
//  - launch_bounds(256,4) (VGPR cap 128; R13 showed tighter caps spill)
// Math (verified absmax 0.0 since R12): norm-augmented 16x16x16 f16 MFMA;
//   A_O=[o_i,|o_i|^2,1,..], B_O=[-2o_j,1,|o_j|^2,..] -> |oi-oj|^2 complete
//   A_P=[p_i,KE*pn_i,1,0], B_P=[M2*p_j,1,KE*pn_j,0] -> finished exp2 arg
// Triangular tile grid, diag tiles mask j>i, x2 folded into final scale.

typedef float v2f __attribute__((ext_vector_type(2)));
typedef float v4f __attribute__((ext_vector_type(4)));
typedef _Float16 h4 __attribute__((ext_vector_type(4)));
typedef float f32x4 __attribute__((ext_vector_type(4)));

constexpr int N_PTS  = 8192;
constexpr int T16    = N_PTS / 16;                // 512 16-row tiles
constexpr int TDIM   = N_PTS / 64;                // 128 64-tiles per side
constexpr int NTILES = TDIM * (TDIM + 1) / 2;     // 8256
constexpr int WPB    = 4;                         // waves per block
constexpr int NBLOCKS = NTILES / WPB;             // 2064

constexpr float KE = -0.72134752044448169f;  // -0.5*log2(e)
constexpr float M2 =  1.4426950408889634f;   // -2*KE = log2(e)

__device__ __forceinline__ int tri_before(int r) {
    return r * TDIM - (r * (r - 1)) / 2;
}

// one thread per (16-tile, lane): emit that lane's A/B fragment words
__global__ __launch_bounds__(256) void cont_prep(
    const float* __restrict__ points, const float* __restrict__ outputs,
    h4* __restrict__ AO, h4* __restrict__ AP,
    h4* __restrict__ BO, h4* __restrict__ BP)
{
    const int idx = blockIdx.x * 256 + threadIdx.x;   // 0..32767
    const int l  = idx & 63;
    const int t  = idx >> 6;
    const int q  = l >> 4, cl = l & 15;
    const int row = t * 16 + cl;

    const v4f* o = reinterpret_cast<const v4f*>(outputs + 8 * row);
    const v4f x = o[0], y = o[1];
    const v4f s = x * x + y * y;
    const float on = (s.x + s.y) + (s.z + s.w);
    const v2f p = reinterpret_cast<const v2f*>(points)[row];
    const float pn = p.x * p.x + p.y * p.y;

    const _Float16 h0 = (_Float16)0.f, h1 = (_Float16)1.f;
    h4 ao, ap, bo, bp;
    if (q == 0)      ao = h4{(_Float16)x.x, (_Float16)x.y, (_Float16)x.z, (_Float16)x.w};
    else if (q == 1) ao = h4{(_Float16)y.x, (_Float16)y.y, (_Float16)y.z, (_Float16)y.w};
    else if (q == 2) ao = h4{(_Float16)on, h1, h0, h0};
    else             ao = h4{h0, h0, h0, h0};
    if (q == 0) ap = h4{(_Float16)p.x, (_Float16)p.y, (_Float16)(KE * pn), h1};
    else        ap = h4{h0, h0, h0, h0};
    if (q == 0)      bo = h4{(_Float16)(-2.f * x.x), (_Float16)(-2.f * x.y),
                             (_Float16)(-2.f * x.z), (_Float16)(-2.f * x.w)};
    else if (q == 1) bo = h4{(_Float16)(-2.f * y.x), (_Float16)(-2.f * y.y),
                             (_Float16)(-2.f * y.z), (_Float16)(-2.f * y.w)};
    else if (q == 2) bo = h4{h1, (_Float16)on, h0, h0};
    else             bo = h4{h0, h0, h0, h0};
    if (q == 0) bp = h4{(_Float16)(M2 * p.x), (_Float16)(M2 * p.y), h1,
                        (_Float16)(KE * pn)};
    else        bp = h4{h0, h0, h0, h0};

    AO[idx] = ao; AP[idx] = ap; BO[idx] = bo; BP[idx] = bp;
}

__global__ __launch_bounds__(256, 4) void cont_pairs(
    const h4* __restrict__ AO, const h4* __restrict__ AP,
    const h4* __restrict__ BO, const h4* __restrict__ BP,
    float* __restrict__ out, double scale)
{
    const int tid  = threadIdx.x;
    const int wid  = tid >> 6;
    const int lane = tid & 63;
    const int g    = blockIdx.x * WPB + wid;     // global tile id, 0..8255

    // closed-form upper-tri decode + exact integer fixup
    int ti = (int)((2 * TDIM + 1 -
                    sqrtf((float)((2 * TDIM + 1) * (2 * TDIM + 1) - 8 * g))) * 0.5f);
    ti = ti < 0 ? 0 : (ti > TDIM - 1 ? TDIM - 1 : ti);
    while (tri_before(ti + 1) <= g) ++ti;
    while (tri_before(ti) > g) --ti;
    const int tj = ti + (g - tri_before(ti));
    const bool diag = (ti == tj);

    const int q = lane >> 4, cl = lane & 15;

    // all fragments loaded up front (coalesced 8B lane loads, latency hoisted)
    h4 aO[4], aP[4], bO[4], bP[4];
    #pragma unroll
    for (int it = 0; it < 4; ++it) {
        const int ta = (ti * 4 + it) * 64 + lane;
        aO[it] = AO[ta]; aP[it] = AP[ta];
        const int tb = (tj * 4 + it) * 64 + lane;
        bO[it] = BO[tb]; bP[it] = BP[tb];
    }

    float accE[4] = {0.f, 0.f, 0.f, 0.f};

    #pragma unroll
    for (int jt = 0; jt < 4; ++jt) {
        const int jcol = jt * 16 + cl;           // C/D col of this lane
        #pragma unroll
        for (int it = 0; it < 4; ++it) {
            const f32x4 z = {0.f, 0.f, 0.f, 0.f};
            f32x4 dO = __builtin_amdgcn_mfma_f32_16x16x16f16(aO[it], bO[jt], z, 0, 0, 0);
            f32x4 dP = __builtin_amdgcn_mfma_f32_16x16x16f16(aP[it], bP[jt], z, 0, 0, 0);
            #pragma unroll
            for (int e = 0; e < 4; ++e) {
                float diff = __builtin_amdgcn_sqrtf(fmaxf(dO[e], 0.f));
                if (diag) {
                    const int irow = it * 16 + q * 4 + e;   // C/D row
                    diff = (jcol > irow) ? diff : 0.f;
                }
                accE[e] = fmaf(__builtin_amdgcn_exp2f(dP[e]), diff, accE[e]);
            }
        }
    }

    float accS = (accE[0] + accE[1]) + (accE[2] + accE[3]);
    #pragma unroll
    for (int off = 32; off > 0; off >>= 1)
        accS += __shfl_down(accS, off, 64);

    __shared__ float wpart[WPB];
    if (lane == 0) wpart[wid] = accS;
    __syncthreads();
    if (tid == 0) {
        double d = 0.0;
        #pragma unroll
        for (int w = 0; w < WPB; ++w) d += (double)wpart[w];
        atomicAdd(out, (float)(d * scale));      // one staggered HW atomic/block
    }
}

extern "C" void kernel_launch(void* const* d_in, const int* in_sizes, int n_in,
                              void* d_out, int out_size, void* d_ws, size_t ws_size,
                              hipStream_t stream) {
    const float* points  = (const float*)d_in[0];
    const float* outputs = (const float*)d_in[1];
    float* out = (float*)d_out;

    const int n = in_sizes[0] / 2;               // 8192
    constexpr size_t TBL = (size_t)T16 * 64 * sizeof(h4);   // 256 KB per table
    h4* AO = (h4*)d_ws;
    h4* AP = (h4*)((char*)d_ws + TBL);
    h4* BO = (h4*)((char*)d_ws + 2 * TBL);
    h4* BP = (h4*)((char*)d_ws + 3 * TBL);

    hipMemsetAsync(d_out, 0, sizeof(float), stream);   // zero the accumulator

    cont_prep<<<dim3(T16 * 64 / 256), dim3(256), 0, stream>>>(
        points, outputs, AO, AP, BO, BP);

    // each unordered pair counted once -> weight 2 folded into the scale
    const double scale = 0.01 * 2.0 / ((double)n * (double)(n - 1));
    cont_pairs<<<dim3(NBLOCKS), dim3(256), 0, stream>>>(
        AO, AP, BO, BP, out, scale);
}

// Round 23
// 23.279 us; speedup vs baseline: 1.8193x; 1.8193x over previous
//
#include <hip/hip_runtime.h>

// ContinuityLoss: loss = 0.01/(n(n-1)) * sum_{i!=j} exp(-|pi-pj|^2/2) * |oi-oj|
// points: [N,2] f32, outputs: [N,8] f32, scalar f32 out. N = 8192.
//
// R22 = R16 verbatim (measured best: 23.1us, absmax 0.0). Final config.
// Optimization history (measured):
//  R0  83.5us  scalar LDS-broadcast baseline (VALUBusy 80%)
//  R1  58.3us  triangular symmetry + SMEM j-side (SMEM-latency bound, 35%)
//  R5  29.4us  LDS broadcast + MROW=2 + 1088 blocks
//  R12 27.7us  norm-augmented 16x16x16 f16 MFMA, 1-wave blocks
//  R14 26.4us  4-wave blocks, launch_bounds(256,4)
//  R16 23.1us  fragment tables hoisted to prep kernel  <- THIS
// Falsified levers: readlane broadcast (-), TLP 2x (0), j-prefetch (0),
//  2x strips (-, VGPR), launch_bounds(256,6) (-, spill->200MB HBM),
//  fused last-block-done w/ fences (-60us), grid-stride 2048 (0),
//  same-address atomic finish (-19us: cross-XCD line convoy).
// Structure:
//  - cont_prep: lane-exact fragment tables AO/AP/BO/BP[512 16-tiles][64]
//    (h4, 1MB total, L2-resident); built once, O(N) work.
//  - cont_pairs: 2064 4-wave blocks; one 64x64 pair-tile per wave;
//    16 coalesced 8B fragment loads + 32 MFMA + {fmax,sqrt,exp2,fma}
//    epilogue; wave shuffle-reduce -> 4-wave LDS reduce -> f64 partial.
//  - cont_final: 1-block f64 reduce of 2064 partials (deterministic).
// Math (hardware-verified absmax 0.0 since R12):
//   A_O=[o_i,|o_i|^2,1,0..], B_O=[-2o_j,1,|o_j|^2,0..] (K=10<=16)
//     -> one mfma_f32_16x16x16f16 emits |oi-oj|^2 complete.
//   A_P=[p_i,KE*pn_i,1,0], B_P=[M2*p_j,1,KE*pn_j,0] (K=4)
//     -> second mfma emits the finished exp2 argument.
//   C/D layout: col=lane&15, row=(lane>>4)*4+reg. Diagonal tiles mask
//   j>i per element; unordered-pair x2 folded into the final scale.

typedef float v2f __attribute__((ext_vector_type(2)));
typedef float v4f __attribute__((ext_vector_type(4)));
typedef _Float16 h4 __attribute__((ext_vector_type(4)));
typedef float f32x4 __attribute__((ext_vector_type(4)));

constexpr int N_PTS  = 8192;
constexpr int T16    = N_PTS / 16;                // 512 16-row tiles
constexpr int TDIM   = N_PTS / 64;                // 128 64-tiles per side
constexpr int NTILES = TDIM * (TDIM + 1) / 2;     // 8256
constexpr int WPB    = 4;                         // waves per block
constexpr int NBLOCKS = NTILES / WPB;             // 2064

constexpr float KE = -0.72134752044448169f;  // -0.5*log2(e)
constexpr float M2 =  1.4426950408889634f;   // -2*KE = log2(e)

__device__ __forceinline__ int tri_before(int r) {
    return r * TDIM - (r * (r - 1)) / 2;
}

// one thread per (16-tile, lane): emit that lane's A/B fragment words
__global__ __launch_bounds__(256) void cont_prep(
    const float* __restrict__ points, const float* __restrict__ outputs,
    h4* __restrict__ AO, h4* __restrict__ AP,
    h4* __restrict__ BO, h4* __restrict__ BP)
{
    const int idx = blockIdx.x * 256 + threadIdx.x;   // 0..32767
    const int l  = idx & 63;
    const int t  = idx >> 6;
    const int q  = l >> 4, cl = l & 15;
    const int row = t * 16 + cl;

    const v4f* o = reinterpret_cast<const v4f*>(outputs + 8 * row);
    const v4f x = o[0], y = o[1];
    const v4f s = x * x + y * y;
    const float on = (s.x + s.y) + (s.z + s.w);
    const v2f p = reinterpret_cast<const v2f*>(points)[row];
    const float pn = p.x * p.x + p.y * p.y;

    const _Float16 h0 = (_Float16)0.f, h1 = (_Float16)1.f;
    h4 ao, ap, bo, bp;
    if (q == 0)      ao = h4{(_Float16)x.x, (_Float16)x.y, (_Float16)x.z, (_Float16)x.w};
    else if (q == 1) ao = h4{(_Float16)y.x, (_Float16)y.y, (_Float16)y.z, (_Float16)y.w};
    else if (q == 2) ao = h4{(_Float16)on, h1, h0, h0};
    else             ao = h4{h0, h0, h0, h0};
    if (q == 0) ap = h4{(_Float16)p.x, (_Float16)p.y, (_Float16)(KE * pn), h1};
    else        ap = h4{h0, h0, h0, h0};
    if (q == 0)      bo = h4{(_Float16)(-2.f * x.x), (_Float16)(-2.f * x.y),
                             (_Float16)(-2.f * x.z), (_Float16)(-2.f * x.w)};
    else if (q == 1) bo = h4{(_Float16)(-2.f * y.x), (_Float16)(-2.f * y.y),
                             (_Float16)(-2.f * y.z), (_Float16)(-2.f * y.w)};
    else if (q == 2) bo = h4{h1, (_Float16)on, h0, h0};
    else             bo = h4{h0, h0, h0, h0};
    if (q == 0) bp = h4{(_Float16)(M2 * p.x), (_Float16)(M2 * p.y), h1,
                        (_Float16)(KE * pn)};
    else        bp = h4{h0, h0, h0, h0};

    AO[idx] = ao; AP[idx] = ap; BO[idx] = bo; BP[idx] = bp;
}

__global__ __launch_bounds__(256, 4) void cont_pairs(
    const h4* __restrict__ AO, const h4* __restrict__ AP,
    const h4* __restrict__ BO, const h4* __restrict__ BP,
    double* __restrict__ partials)
{
    const int tid  = threadIdx.x;
    const int wid  = tid >> 6;
    const int lane = tid & 63;
    const int g    = blockIdx.x * WPB + wid;     // global tile id, 0..8255

    // closed-form upper-tri decode + exact integer fixup
    int ti = (int)((2 * TDIM + 1 -
                    sqrtf((float)((2 * TDIM + 1) * (2 * TDIM + 1) - 8 * g))) * 0.5f);
    ti = ti < 0 ? 0 : (ti > TDIM - 1 ? TDIM - 1 : ti);
    while (tri_before(ti + 1) <= g) ++ti;
    while (tri_before(ti) > g) --ti;
    const int tj = ti + (g - tri_before(ti));
    const bool diag = (ti == tj);

    const int q = lane >> 4, cl = lane & 15;

    // all fragments loaded up front (coalesced 8B lane loads, latency hoisted)
    h4 aO[4], aP[4], bO[4], bP[4];
    #pragma unroll
    for (int it = 0; it < 4; ++it) {
        const int ta = (ti * 4 + it) * 64 + lane;
        aO[it] = AO[ta]; aP[it] = AP[ta];
        const int tb = (tj * 4 + it) * 64 + lane;
        bO[it] = BO[tb]; bP[it] = BP[tb];
    }

    float accE[4] = {0.f, 0.f, 0.f, 0.f};

    #pragma unroll
    for (int jt = 0; jt < 4; ++jt) {
        const int jcol = jt * 16 + cl;           // C/D col of this lane
        #pragma unroll
        for (int it = 0; it < 4; ++it) {
            const f32x4 z = {0.f, 0.f, 0.f, 0.f};
            f32x4 dO = __builtin_amdgcn_mfma_f32_16x16x16f16(aO[it], bO[jt], z, 0, 0, 0);
            f32x4 dP = __builtin_amdgcn_mfma_f32_16x16x16f16(aP[it], bP[jt], z, 0, 0, 0);
            #pragma unroll
            for (int e = 0; e < 4; ++e) {
                float diff = __builtin_amdgcn_sqrtf(fmaxf(dO[e], 0.f));
                if (diag) {
                    const int irow = it * 16 + q * 4 + e;   // C/D row
                    diff = (jcol > irow) ? diff : 0.f;
                }
                accE[e] = fmaf(__builtin_amdgcn_exp2f(dP[e]), diff, accE[e]);
            }
        }
    }

    float accS = (accE[0] + accE[1]) + (accE[2] + accE[3]);
    #pragma unroll
    for (int off = 32; off > 0; off >>= 1)
        accS += __shfl_down(accS, off, 64);

    __shared__ float wpart[WPB];
    if (lane == 0) wpart[wid] = accS;
    __syncthreads();
    if (tid == 0) {
        double d = 0.0;
        #pragma unroll
        for (int w = 0; w < WPB; ++w) d += (double)wpart[w];
        partials[blockIdx.x] = d;
    }
}

__global__ __launch_bounds__(1024) void cont_final(
    const double* __restrict__ partials, int nparts,
    float* __restrict__ out, double scale)
{
    const int tid = threadIdx.x;
    double sum = 0.0;
    for (int i = tid; i < nparts; i += 1024) sum += partials[i];
    #pragma unroll
    for (int off = 32; off > 0; off >>= 1)
        sum += __shfl_down(sum, off, 64);

    __shared__ double ws[1024 / 64];
    if ((tid & 63) == 0) ws[tid >> 6] = sum;
    __syncthreads();
    if (tid == 0) {
        double t = 0.0;
        #pragma unroll
        for (int w = 0; w < 1024 / 64; ++w) t += ws[w];
        out[0] = (float)(t * scale);
    }
}

extern "C" void kernel_launch(void* const* d_in, const int* in_sizes, int n_in,
                              void* d_out, int out_size, void* d_ws, size_t ws_size,
                              hipStream_t stream) {
    const float* points  = (const float*)d_in[0];
    const float* outputs = (const float*)d_in[1];
    float* out = (float*)d_out;

    const int n = in_sizes[0] / 2;               // 8192
    constexpr size_t TBL = (size_t)T16 * 64 * sizeof(h4);   // 256 KB per table
    h4* AO = (h4*)d_ws;
    h4* AP = (h4*)((char*)d_ws + TBL);
    h4* BO = (h4*)((char*)d_ws + 2 * TBL);
    h4* BP = (h4*)((char*)d_ws + 3 * TBL);
    double* partials = (double*)((char*)d_ws + 4 * TBL);    // 2064 * 8B

    cont_prep<<<dim3(T16 * 64 / 256), dim3(256), 0, stream>>>(
        points, outputs, AO, AP, BO, BP);
    cont_pairs<<<dim3(NBLOCKS), dim3(256), 0, stream>>>(AO, AP, BO, BP, partials);

    // each unordered pair counted once -> weight 2 folded into the scale
    const double scale = 0.01 * 2.0 / ((double)n * (double)(n - 1));
    cont_final<<<1, 1024, 0, stream>>>(partials, NBLOCKS, out, scale);
}